// Round 7
// baseline (179.312 us; speedup 1.0000x reference)
//
#include <hip/hip_runtime.h>
#include <hip/hip_cooperative_groups.h>

namespace cg = cooperative_groups;

// LFQ forward, single cooperative kernel for MI355X (gfx950).
// Outputs in d_out (float32): out[16384*512], indices[16384] (as float), aux_loss[1]
// ws layout: P[256][4096] partials (4 MB) | scal {C_sum, E_sum, done_count}

#define NS    16384      // samples = 4*4096
#define NOUT  (NS*512)   // 8388608
#define AUXO  (NOUT+NS)  // 8404992
#define INVT2 200.0f     // 2 * inv_temperature
#define NBLK  256        // one block per CU (cooperative co-residency)
#define RBLK  64         // blocks participating in the final reduce

// DPP-based butterfly add step, bitwise-equal to  v += __shfl_xor(v, m)  for
// m=1 (0xB1), m=2 (0x4E), m=4 (0x141 half_mirror; quads uniform after 1,2),
// m=8 (0x140 mirror; 8-groups uniform after 4). VALU pipe, no DS traffic.
template <int CTRL>
__device__ inline float dpp_add(float v) {
  int p = __builtin_amdgcn_update_dpp(0, __float_as_int(v), CTRL, 0xF, 0xF, true);
  return v + __int_as_float(p);
}
__device__ inline float rdlane(float v, int lane) {
  return __int_as_float(__builtin_amdgcn_readlane(__float_as_int(v), lane));
}

__global__ __launch_bounds__(512, 2) void k_all(
    const float* __restrict__ x,
    const float* __restrict__ w_in,  const float* __restrict__ b_in,
    const float* __restrict__ w_out, const float* __restrict__ b_out,
    float* __restrict__ out, float* __restrict__ idx_out,
    float* __restrict__ P, float* __restrict__ scal, float* __restrict__ aux) {

  __shared__ float s_wi[6144];      // w_in swizzled: [d][e4][sub] float4s (dot partition)
  __shared__ float s_wt[6144];      // w_out^T swizzled for coalesced store partition
  __shared__ float s_phi[64][64];   // per-sample high-6-bit softmax probs
  __shared__ float s_psi[64][64];   // per-sample low-6-bit softmax probs
  __shared__ float s_xp[8][8][12];  // per-wave xp broadcast
  __shared__ float s_h[8];
  __shared__ float red[8][64];      // phase-C column partials

  const int t   = threadIdx.x;
  const int bid = blockIdx.x;

  // ================= phase A: projection (R1 body, bitwise-proven) =================
  // s_wi: element (d, e) with e = sub*32 + e4*4 + kk stored at f = ((d*128+e4*16+sub)*4+kk).
  // s_wt: float f = d*512 + e holds w_out[e][d]  -> out-proj reads give coalesced stores.
  for (int k = 0; k < 12; ++k) {
    int f  = t + k * 512;
    int kk = f & 3;
    int q  = f >> 2;
    int sub = q & 15, e4 = (q >> 4) & 7, d = q >> 7;
    int e  = sub * 32 + e4 * 4 + kk;
    s_wi[f] = w_in[d * 512 + e];
    s_wt[f] = w_out[t * 12 + k];   // f = t + k*512 -> e = t, d = k
  }
  if (bid == 0 && t == 0) {        // zero accumulators; consumed only after grid sync #1
    scal[0] = 0.f; scal[1] = 0.f; ((unsigned*)scal)[2] = 0u;
  }
  __syncthreads();

  const int wave = t >> 6, lane = t & 63;
  const int g = lane >> 4, sub = lane & 15;

  float bin[12];
  #pragma unroll
  for (int d = 0; d < 12; ++d) bin[d] = b_in[d];

  // two samples per lane (weight reads amortized)
  const int i0 = bid * 64 + wave * 8 + g;
  const int i1 = i0 + 4;

  const float4* xr0 = (const float4*)(x + (size_t)i0 * 512 + sub * 32);
  const float4* xr1 = (const float4*)(x + (size_t)i1 * 512 + sub * 32);
  float4 xv0[8], xv1[8];
  #pragma unroll
  for (int e4 = 0; e4 < 8; ++e4) { xv0[e4] = xr0[e4]; xv1[e4] = xr1[e4]; }

  float p0[12], p1[12];
  #pragma unroll
  for (int d = 0; d < 12; ++d) { p0[d] = 0.f; p1[d] = 0.f; }
  #pragma unroll
  for (int e4 = 0; e4 < 8; ++e4) {
    #pragma unroll
    for (int d = 0; d < 12; ++d) {
      float4 w4 = ((const float4*)s_wi)[d * 128 + e4 * 16 + sub];
      p0[d] += xv0[e4].x * w4.x + xv0[e4].y * w4.y + xv0[e4].z * w4.z + xv0[e4].w * w4.w;
      p1[d] += xv1[e4].x * w4.x + xv1[e4].y * w4.y + xv1[e4].z * w4.z + xv1[e4].w * w4.w;
    }
  }
  #pragma unroll
  for (int d = 0; d < 12; ++d) {
    #pragma unroll
    for (int m = 1; m <= 8; m <<= 1) {
      p0[d] += __shfl_xor(p0[d], m, 16);
      p1[d] += __shfl_xor(p1[d], m, 16);
    }
    p0[d] += bin[d];
    p1[d] += bin[d];
  }

  unsigned idx0 = 0u, idx1 = 0u;
  #pragma unroll
  for (int d = 0; d < 12; ++d) {
    idx0 |= (p0[d] > 0.f ? 1u : 0u) << (11 - d);
    idx1 |= (p1[d] > 0.f ? 1u : 0u) << (11 - d);
  }
  if (sub == 0) {
    idx_out[i0] = (float)idx0;
    idx_out[i1] = (float)idx1;
    #pragma unroll
    for (int d = 0; d < 12; ++d) {
      s_xp[wave][g][d]     = p0[d];
      s_xp[wave][4 + g][d] = p1[d];
    }
  }

  // out rows (coalesced store partition, bitwise-proven)
  float sg0[12], sg1[12];
  #pragma unroll
  for (int d = 0; d < 12; ++d) {
    sg0[d] = p0[d] > 0.f ? 1.f : -1.f;
    sg1[d] = p1[d] > 0.f ? 1.f : -1.f;
  }
  float4* or0 = (float4*)(out + (size_t)i0 * 512);
  float4* or1 = (float4*)(out + (size_t)i1 * 512);
  #pragma unroll
  for (int e4 = 0; e4 < 8; ++e4) {
    float4 bo = ((const float4*)b_out)[e4 * 16 + sub];
    float4 o0 = bo, o1 = bo;
    #pragma unroll
    for (int d = 0; d < 12; ++d) {
      float4 w4 = ((const float4*)s_wt)[d * 128 + e4 * 16 + sub];
      o0.x += sg0[d] * w4.x; o0.y += sg0[d] * w4.y; o0.z += sg0[d] * w4.z; o0.w += sg0[d] * w4.w;
      o1.x += sg1[d] * w4.x; o1.y += sg1[d] * w4.y; o1.z += sg1[d] * w4.z; o1.w += sg1[d] * w4.w;
    }
    or0[e4 * 16 + sub] = o0;
    or1[e4 * 16 + sub] = o1;
  }

  // ============ phase B: entropy (DPP, bitwise-proven) + avg_prob partials ============
  float hacc = 0.f;
  #pragma unroll 1
  for (int s = 0; s < 8; ++s) {
    float xq[12];
    #pragma unroll
    for (int d = 0; d < 12; ++d) xq[d] = s_xp[wave][s][d];   // same-wave LDS, no barrier

    float hi = 0.f, lo = 0.f, ah = 0.f, al = 0.f;
    #pragma unroll
    for (int d = 0; d < 6; ++d) {
      int bh = (lane >> (5 - d)) & 1;
      hi += bh ? xq[d]     : -xq[d];
      lo += bh ? xq[6 + d] : -xq[6 + d];
      ah += fabsf(xq[d]);
      al += fabsf(xq[6 + d]);
    }
    float lhi = INVT2 * (hi - ah);   // <= 0, max over lanes == 0
    float llo = INVT2 * (lo - al);
    float ehi = __expf(lhi);
    float elo = __expf(llo);

    float Shi = ehi, Slo = elo;
    Shi = dpp_add<0xB1>(Shi);  Slo = dpp_add<0xB1>(Slo);   // xor 1
    Shi = dpp_add<0x4E>(Shi);  Slo = dpp_add<0x4E>(Slo);   // xor 2
    Shi = dpp_add<0x141>(Shi); Slo = dpp_add<0x141>(Slo);  // xor 4 (half_mirror)
    Shi = dpp_add<0x140>(Shi); Slo = dpp_add<0x140>(Slo);  // xor 8 (mirror)
    {
      float r0 = rdlane(Shi, 0), r1 = rdlane(Shi, 16), r2 = rdlane(Shi, 32), r3 = rdlane(Shi, 48);
      Shi = (r0 + r1) + (r2 + r3);
      float q0 = rdlane(Slo, 0), q1 = rdlane(Slo, 16), q2 = rdlane(Slo, 32), q3 = rdlane(Slo, 48);
      Slo = (q0 + q1) + (q2 + q3);
    }

    float phi = ehi / Shi;
    float psi = elo / Slo;
    float lnShi = __logf(Shi), lnSlo = __logf(Slo);
    hacc += phi * (lhi - lnShi) + psi * (llo - lnSlo);

    s_phi[wave * 8 + s][lane] = phi;
    s_psi[wave * 8 + s][lane] = psi;
  }

  #pragma unroll
  for (int m = 1; m <= 32; m <<= 1) hacc += __shfl_xor(hacc, m);
  if (lane == 0) s_h[wave] = hacc;
  __syncthreads();   // publishes s_phi/s_psi/s_h

  float hs = 0.f;
  if (t == 0) {
    #pragma unroll
    for (int w2 = 0; w2 < 8; ++w2) hs += s_h[w2];
  }

  // avg_prob partials: P[j][l] = sum_s phi[s][j]*psi[s][l]; 4(j) x 2(l) per thread
  {
    const int jb = (t >> 5) * 4;
    const int lb = (t & 31) * 2;
    float a00 = 0.f, a01 = 0.f, a10 = 0.f, a11 = 0.f;
    float a20 = 0.f, a21 = 0.f, a30 = 0.f, a31 = 0.f;
    #pragma unroll 4
    for (int s = 0; s < 64; ++s) {
      float4 ph = *(const float4*)&s_phi[s][jb];
      float2 ps = *(const float2*)&s_psi[s][lb];
      a00 += ph.x * ps.x; a01 += ph.x * ps.y;
      a10 += ph.y * ps.x; a11 += ph.y * ps.y;
      a20 += ph.z * ps.x; a21 += ph.z * ps.y;
      a30 += ph.w * ps.x; a31 += ph.w * ps.y;
    }
    float* Pr = P + (size_t)bid * 4096;
    *(float2*)&Pr[(jb + 0) * 64 + lb] = make_float2(a00, a01);
    *(float2*)&Pr[(jb + 1) * 64 + lb] = make_float2(a10, a11);
    *(float2*)&Pr[(jb + 2) * 64 + lb] = make_float2(a20, a21);
    *(float2*)&Pr[(jb + 3) * 64 + lb] = make_float2(a30, a31);
  }

  // ============ grid sync #1: scal zeroing + P visible; then Csum atomics ============
  cg::this_grid().sync();
  if (t == 0) atomicAdd(&scal[0], hs);
  cg::this_grid().sync();

  // ================= phase C: reduce partials, codebook entropy, aux =================
  if (bid < RBLK) {
    const int c  = bid * 64 + (t & 63);
    const int rg = t >> 6;                  // 8 row-groups of 32 rows
    float s = 0.f;
    #pragma unroll 8
    for (int j = 0; j < 32; ++j) s += P[(size_t)(rg * 32 + j) * 4096 + c];
    red[rg][t & 63] = s;
    __syncthreads();
    if (t < 64) {
      float tot = (((red[0][t] + red[1][t]) + (red[2][t] + red[3][t])) +
                   ((red[4][t] + red[5][t]) + (red[6][t] + red[7][t])));
      float pb = tot * (1.f / (float)NS);
      float e = pb * __logf(fmaxf(pb, 1e-5f));   // p * log(clip(p, eps))
      #pragma unroll
      for (int m = 1; m <= 32; m <<= 1) e += __shfl_xor(e, m);
      if (t == 0) {
        atomicAdd(&scal[1], e);
        __threadfence();
        unsigned done = atomicAdd((unsigned*)&scal[2], 1u);
        if (done == RBLK - 1) {   // last reduce block: final combine
          float E = atomicAdd(&scal[1], 0.f);   // coherent reads via atomic
          float C = atomicAdd(&scal[0], 0.f);
          float per_sample_entropy = -C * (1.f / (float)NS);
          float codebook_entropy   = -E;
          aux[0] = 0.1f * (per_sample_entropy - codebook_entropy);
        }
      }
    }
  }
}

extern "C" void kernel_launch(void* const* d_in, const int* in_sizes, int n_in,
                              void* d_out, int out_size, void* d_ws, size_t ws_size,
                              hipStream_t stream) {
  const float* x     = (const float*)d_in[0];
  const float* w_in  = (const float*)d_in[1];
  const float* b_in  = (const float*)d_in[2];
  const float* w_out = (const float*)d_in[3];
  const float* b_out = (const float*)d_in[4];
  float* out     = (float*)d_out;
  float* idx_out = out + NOUT;
  float* aux     = out + AUXO;

  float* P    = (float*)d_ws;                 // 256*4096 f32 = 4 MB
  float* scal = P + (size_t)NBLK * 4096;      // {C_sum, E_sum, done}

  void* args[] = { (void*)&x, (void*)&w_in, (void*)&b_in, (void*)&w_out, (void*)&b_out,
                   (void*)&out, (void*)&idx_out, (void*)&P, (void*)&scal, (void*)&aux };
  hipLaunchCooperativeKernel((const void*)k_all, dim3(NBLK), dim3(512), args, 0, stream);
}

// Round 8
// 122.625 us; speedup vs baseline: 1.4623x; 1.4623x over previous
//
#include <hip/hip_runtime.h>
#include <hip/hip_bf16.h>

// LFQ forward for MI355X (gfx950) — 3 dispatches, each shaped for its bottleneck.
// Outputs in d_out (float32): out[16384*512], indices[16384] (as float), aux_loss[1]
// ws layout: T[4096][512] (8 MB) | P[256][4096] (4 MB) | xp[16384][12] (786 KB) | scal

#define NS    16384      // samples = 4*4096
#define NOUT  (NS*512)   // 8388608
#define AUXO  (NOUT+NS)  // 8404992
#define INVT2 200.0f     // 2 * inv_temperature
#define TBLK  64         // kA table blocks
#define DBLK  1024       // kA dot blocks (16 samples each)
#define EBLK  256        // kB entropy blocks (64 samples each)
#define GBLK  512        // kB gather blocks (32 rows each)
#define RBLK  64         // kC blocks

// DPP-based butterfly add, bitwise-equal to v += __shfl_xor(v, m) for
// m=1 (0xB1), m=2 (0x4E), m=4 (0x141 half_mirror; quads uniform after 1,2),
// m=8 (0x140 mirror; 8-groups uniform after 4). VALU pipe, no DS traffic.
template <int CTRL>
__device__ inline float dpp_add(float v) {
  int p = __builtin_amdgcn_update_dpp(0, __float_as_int(v), CTRL, 0xF, 0xF, true);
  return v + __int_as_float(p);
}
__device__ inline float rdlane(float v, int lane) {
  return __int_as_float(__builtin_amdgcn_readlane(__float_as_int(v), lane));
}

// -------- kA: blocks [0,64) build T (R3-proven bitwise); blocks [64,1088) = dot-only.
__global__ __launch_bounds__(256) void kA(
    const float* __restrict__ x,
    const float* __restrict__ w_in,  const float* __restrict__ b_in,
    const float* __restrict__ w_out, const float* __restrict__ b_out,
    float* __restrict__ T, float* __restrict__ idx_out,
    float* __restrict__ xp_out, float* __restrict__ scal) {

  __shared__ float s_w[6144];   // table: w_out^T swizzle | dot: w_in swizzle
  const int bid = blockIdx.x;
  const int t   = threadIdx.x;

  if (bid < TBLK) {
    // ---- table: T[c][e] = b_out[e] + sum_d sg_d(c) * w_out[e][d]
    // s_w[f], f = d*512 + e, holds w_out[e][d] (same layout as R3's s_wt).
    #pragma unroll
    for (int k = 0; k < 12; ++k) {
      s_w[t + k * 512]         = w_out[t * 12 + k];
      s_w[t + 256 + k * 512]   = w_out[(t + 256) * 12 + k];
    }
    if (bid == 0 && t == 0) { scal[0] = 0.f; scal[1] = 0.f; ((unsigned*)scal)[2] = 0u; }
    __syncthreads();

    const int c = bid * 64 + (t >> 2);          // 64 codes/block; 4 threads/code
    float sg[12];
    #pragma unroll
    for (int d = 0; d < 12; ++d) sg[d] = ((c >> (11 - d)) & 1) ? 1.f : -1.f;

    float4* Trow = (float4*)(T + (size_t)c * 512);
    const float4* bo4 = (const float4*)b_out;
    const float4* wt4 = (const float4*)s_w;
    #pragma unroll 8
    for (int j = 0; j < 32; ++j) {
      const int m = (t & 3) + 4 * j;            // float4 index in the 512-row
      float4 o = bo4[m];
      #pragma unroll
      for (int d = 0; d < 12; ++d) {
        float4 w4 = wt4[d * 128 + m];
        o.x += sg[d] * w4.x; o.y += sg[d] * w4.y; o.z += sg[d] * w4.z; o.w += sg[d] * w4.w;
      }
      Trow[m] = o;
    }
    return;
  }

  // ---- dot: 16 samples/block, one per 16-lane group (R2-proven body).
  // s_w holds w_in swizzled: element (d,e), e = sub*32+e4*4+kk at ((d*128+e4*16+sub)*4+kk).
  // Staging reads w_in LINEARLY (coalesced) and scatters into LDS (2-way conflicts, free).
  #pragma unroll
  for (int k = 0; k < 24; ++k) {
    const int f = t + k * 256;                  // linear w_in index
    const int d = f >> 9, e = f & 511;
    const int pos = ((d * 128 + ((e >> 2) & 7) * 16 + (e >> 5)) << 2) | (e & 3);
    s_w[pos] = w_in[f];
  }
  __syncthreads();

  const int wave = t >> 6, lane = t & 63;
  const int g = lane >> 4, sub = lane & 15;

  float bin[12];
  #pragma unroll
  for (int d = 0; d < 12; ++d) bin[d] = b_in[d];

  const int i0 = (bid - TBLK) * 16 + wave * 4 + g;

  const float4* xr0 = (const float4*)(x + (size_t)i0 * 512 + sub * 32);
  float4 xv0[8];
  #pragma unroll
  for (int e4 = 0; e4 < 8; ++e4) xv0[e4] = xr0[e4];

  float p0[12];
  #pragma unroll
  for (int d = 0; d < 12; ++d) p0[d] = 0.f;
  #pragma unroll
  for (int e4 = 0; e4 < 8; ++e4) {
    #pragma unroll
    for (int d = 0; d < 12; ++d) {
      float4 w4 = ((const float4*)s_w)[d * 128 + e4 * 16 + sub];
      p0[d] += xv0[e4].x * w4.x + xv0[e4].y * w4.y + xv0[e4].z * w4.z + xv0[e4].w * w4.w;
    }
  }
  #pragma unroll
  for (int d = 0; d < 12; ++d) {
    #pragma unroll
    for (int m = 1; m <= 8; m <<= 1) p0[d] += __shfl_xor(p0[d], m, 16);
    p0[d] += bin[d];
  }

  unsigned idx0 = 0u;
  #pragma unroll
  for (int d = 0; d < 12; ++d) idx0 |= (p0[d] > 0.f ? 1u : 0u) << (11 - d);
  if (sub == 0) idx_out[i0] = (float)idx0;

  // xp spill (R6-proven): lanes sub=0..2 write one float4 each, static components
  {
    float4 v0 = make_float4(p0[0], p0[1], p0[2], p0[3]);
    if (sub == 1) v0 = make_float4(p0[4], p0[5], p0[6], p0[7]);
    if (sub == 2) v0 = make_float4(p0[8], p0[9], p0[10], p0[11]);
    if (sub < 3) ((float4*)(xp_out + (size_t)i0 * 12))[sub] = v0;
  }
}

// -------- kB: blocks [0,256) = entropy + P partials (R5/R6-proven DPP body);
//             blocks [256,768) = out-gather stream out[i] = T[idx[i]].
__global__ __launch_bounds__(256) void kB(
    const float* __restrict__ T, const float* __restrict__ idx_f,
    const float* __restrict__ xp,
    float* __restrict__ out, float* __restrict__ P, float* __restrict__ scal) {

  __shared__ float s_phi[64][64];
  __shared__ float s_psi[64][64];
  __shared__ float s_h[4];

  const int bid = blockIdx.x, t = threadIdx.x;
  const int wave = t >> 6, lane = t & 63;

  if (bid >= EBLK) {
    // ---- gather: 32 rows/block, 8 per wave; pure BW stream, coalesced 256 B chunks
    const int base = (bid - EBLK) * 32 + wave * 8;
    #pragma unroll
    for (int r = 0; r < 8; ++r) {
      const int i = base + r;
      const unsigned c = (unsigned)idx_f[i];     // exact (<=4095)
      const float4* Tr = (const float4*)(T + (size_t)c * 512);
      float4* orow = (float4*)(out + (size_t)i * 512);
      orow[lane]      = Tr[lane];
      orow[lane + 64] = Tr[lane + 64];
    }
    return;
  }

  // ---- entropy: 64 samples/block, 16 per wave
  const int sbase = bid * 64 + wave * 16;
  float hacc = 0.f;
  #pragma unroll 1
  for (int s = 0; s < 16; ++s) {
    const float* xps = xp + (size_t)(sbase + s) * 12;   // wave-uniform -> scalar loads
    float xq[12];
    #pragma unroll
    for (int d = 0; d < 12; ++d) xq[d] = xps[d];

    float hi = 0.f, lo = 0.f, ah = 0.f, al = 0.f;
    #pragma unroll
    for (int d = 0; d < 6; ++d) {
      int bh = (lane >> (5 - d)) & 1;
      hi += bh ? xq[d]     : -xq[d];
      lo += bh ? xq[6 + d] : -xq[6 + d];
      ah += fabsf(xq[d]);
      al += fabsf(xq[6 + d]);
    }
    float lhi = INVT2 * (hi - ah);   // <= 0, max over lanes == 0
    float llo = INVT2 * (lo - al);
    float ehi = __expf(lhi);
    float elo = __expf(llo);

    float Shi = ehi, Slo = elo;
    Shi = dpp_add<0xB1>(Shi);  Slo = dpp_add<0xB1>(Slo);   // xor 1
    Shi = dpp_add<0x4E>(Shi);  Slo = dpp_add<0x4E>(Slo);   // xor 2
    Shi = dpp_add<0x141>(Shi); Slo = dpp_add<0x141>(Slo);  // xor 4 (half_mirror)
    Shi = dpp_add<0x140>(Shi); Slo = dpp_add<0x140>(Slo);  // xor 8 (mirror)
    {
      float r0 = rdlane(Shi, 0), r1 = rdlane(Shi, 16), r2 = rdlane(Shi, 32), r3 = rdlane(Shi, 48);
      Shi = (r0 + r1) + (r2 + r3);
      float q0 = rdlane(Slo, 0), q1 = rdlane(Slo, 16), q2 = rdlane(Slo, 32), q3 = rdlane(Slo, 48);
      Slo = (q0 + q1) + (q2 + q3);
    }

    float phi = ehi / Shi;
    float psi = elo / Slo;
    float lnShi = __logf(Shi), lnSlo = __logf(Slo);
    hacc += phi * (lhi - lnShi) + psi * (llo - lnSlo);

    s_phi[wave * 16 + s][lane] = phi;
    s_psi[wave * 16 + s][lane] = psi;
  }

  #pragma unroll
  for (int m = 1; m <= 32; m <<= 1) hacc += __shfl_xor(hacc, m);
  if (lane == 0) s_h[wave] = hacc;
  __syncthreads();   // publishes s_phi/s_psi/s_h
  if (t == 0) atomicAdd(&scal[0], (s_h[0] + s_h[1]) + (s_h[2] + s_h[3]));

  // phase B: P[j][l] = sum_s phi[s][j]*psi[s][l]; each thread owns 4(j) x 4(l)
  const int jb = (t >> 4) * 4;   // 16 j-tiles of 4
  const int lb = (t & 15) * 4;   // 16 l-tiles of 4
  float4 r0 = {0,0,0,0}, r1 = {0,0,0,0}, r2 = {0,0,0,0}, r3 = {0,0,0,0};
  #pragma unroll 4
  for (int s = 0; s < 64; ++s) {
    float4 ph = *(const float4*)&s_phi[s][jb];
    float4 ps = *(const float4*)&s_psi[s][lb];
    r0.x += ph.x * ps.x; r0.y += ph.x * ps.y; r0.z += ph.x * ps.z; r0.w += ph.x * ps.w;
    r1.x += ph.y * ps.x; r1.y += ph.y * ps.y; r1.z += ph.y * ps.z; r1.w += ph.y * ps.w;
    r2.x += ph.z * ps.x; r2.y += ph.z * ps.y; r2.z += ph.z * ps.z; r2.w += ph.z * ps.w;
    r3.x += ph.w * ps.x; r3.y += ph.w * ps.y; r3.z += ph.w * ps.z; r3.w += ph.w * ps.w;
  }
  float* Pr = P + (size_t)bid * 4096;
  *(float4*)&Pr[(jb + 0) * 64 + lb] = r0;
  *(float4*)&Pr[(jb + 1) * 64 + lb] = r1;
  *(float4*)&Pr[(jb + 2) * 64 + lb] = r2;
  *(float4*)&Pr[(jb + 3) * 64 + lb] = r3;
}

// -------- kC: reduce P -> avg_prob, codebook entropy; last block emits aux_loss.
__global__ __launch_bounds__(256) void kC(const float* __restrict__ P,
                                          float* __restrict__ scal,
                                          float* __restrict__ aux) {
  __shared__ float red[4][64];
  const int t = threadIdx.x;
  const int c = blockIdx.x * 64 + (t & 63);
  const int rg = t >> 6;                       // 4 row-groups of 64 rows
  float s = 0.f;
  #pragma unroll 8
  for (int j = 0; j < 64; ++j) s += P[(size_t)(rg * 64 + j) * 4096 + c];
  red[rg][t & 63] = s;
  __syncthreads();
  if (t < 64) {
    float tot = (red[0][t] + red[1][t]) + (red[2][t] + red[3][t]);
    float pb = tot * (1.f / (float)NS);
    float e = pb * __logf(fmaxf(pb, 1e-5f));   // p * log(clip(p, eps))
    #pragma unroll
    for (int m = 1; m <= 32; m <<= 1) e += __shfl_xor(e, m);
    if (t == 0) {
      atomicAdd(&scal[1], e);
      __threadfence();
      unsigned done = atomicAdd((unsigned*)&scal[2], 1u);
      if (done == RBLK - 1) {   // last block: final combine
        float E = atomicAdd(&scal[1], 0.f);   // coherent reads via atomic
        float C = atomicAdd(&scal[0], 0.f);
        float per_sample_entropy = -C * (1.f / (float)NS);
        float codebook_entropy   = -E;
        aux[0] = 0.1f * (per_sample_entropy - codebook_entropy);
      }
    }
  }
}

extern "C" void kernel_launch(void* const* d_in, const int* in_sizes, int n_in,
                              void* d_out, int out_size, void* d_ws, size_t ws_size,
                              hipStream_t stream) {
  const float* x     = (const float*)d_in[0];
  const float* w_in  = (const float*)d_in[1];
  const float* b_in  = (const float*)d_in[2];
  const float* w_out = (const float*)d_in[3];
  const float* b_out = (const float*)d_in[4];
  float* out     = (float*)d_out;
  float* idx_out = out + NOUT;
  float* aux     = out + AUXO;

  float* T    = (float*)d_ws;                 // 4096*512 f32 = 8 MB
  float* P    = T + (size_t)4096 * 512;       // 256*4096 f32 = 4 MB
  float* xp   = P + (size_t)EBLK * 4096;      // 16384*12 f32 = 786 KB
  float* scal = xp + (size_t)NS * 12;         // {C_sum, E_sum, done}

  kA<<<TBLK + DBLK, 256, 0, stream>>>(x, w_in, b_in, w_out, b_out, T, idx_out, xp, scal);
  kB<<<EBLK + GBLK, 256, 0, stream>>>(T, idx_out, xp, out, P, scal);
  kC<<<RBLK, 256, 0, stream>>>(P, scal, aux);
}

// Round 9
// 116.797 us; speedup vs baseline: 1.5352x; 1.0499x over previous
//
#include <hip/hip_runtime.h>
#include <hip/hip_bf16.h>

// LFQ forward fused kernels for MI355X (gfx950) — 2 dispatches.
// Outputs in d_out (float32): out[16384*512], indices[16384] (as float), aux_loss[1]
// ws layout: P[512][4096] partials (8 MB) | Hpart[512] | scal {C_sum, E_sum, done}

#define NS    16384      // samples = 4*4096
#define NOUT  (NS*512)   // 8388608
#define AUXO  (NOUT+NS)  // 8404992
#define INVT2 200.0f     // 2 * inv_temperature
#define NBLK  512        // K1 blocks; 32 samples each
#define RBLK  64         // K2 blocks

// -------- K1: xp, indices, out-projection, factorized softmax entropy + avg_prob partials
// R2-champion body, unchanged. Only the scalar epilogue differs: block entropy sum goes to
// Hpart[bid] (plain store, no atomic), and block 0 zeroes scal (consumed only by K2).
__global__ __launch_bounds__(512, 4) void k_main(
    const float* __restrict__ x,
    const float* __restrict__ w_in,  const float* __restrict__ b_in,
    const float* __restrict__ w_out, const float* __restrict__ b_out,
    float* __restrict__ out, float* __restrict__ idx_out,
    float* __restrict__ P, float* __restrict__ Hpart, float* __restrict__ scal) {

  __shared__ float s_wi[6144];      // w_in swizzled: [d][e4][sub] float4s (dot partition)
  __shared__ float s_wt[6144];      // w_out^T swizzled for coalesced store partition
  __shared__ float s_phi[32][64];   // per-sample high-6-bit softmax probs
  __shared__ float s_psi[32][64];   // per-sample low-6-bit softmax probs
  __shared__ float s_xp[8][4][12];  // per-wave xp broadcast
  __shared__ float s_h[8];

  const int t = threadIdx.x;

  // stage weights (same swizzles as the 113.7-champion kernel)
  for (int k = 0; k < 12; ++k) {
    int f  = t + k * 512;
    int kk = f & 3;
    int q  = f >> 2;
    int sub = q & 15, e4 = (q >> 4) & 7, d = q >> 7;
    int e  = sub * 32 + e4 * 4 + kk;
    s_wi[f] = w_in[d * 512 + e];
    s_wt[f] = w_out[t * 12 + k];   // f = t + k*512 -> e = t, d = k
  }
  if (blockIdx.x == 0 && t == 0) { // zero K2's accumulators; K1 never touches them again
    scal[0] = 0.f; scal[1] = 0.f; ((unsigned*)scal)[2] = 0u;
  }
  __syncthreads();

  const int wave = t >> 6, lane = t & 63;
  const int g = lane >> 4, sub = lane & 15;

  float bin[12];
  #pragma unroll
  for (int d = 0; d < 12; ++d) bin[d] = b_in[d];

  // ---- one sample per lane-group
  const int i0 = blockIdx.x * 32 + wave * 4 + g;

  const float4* xr0 = (const float4*)(x + (size_t)i0 * 512 + sub * 32);
  float4 xv0[8];
  #pragma unroll
  for (int e4 = 0; e4 < 8; ++e4) xv0[e4] = xr0[e4];

  // ---- partial dots for 12 dims
  float p0[12];
  #pragma unroll
  for (int d = 0; d < 12; ++d) p0[d] = 0.f;
  #pragma unroll
  for (int e4 = 0; e4 < 8; ++e4) {
    #pragma unroll
    for (int d = 0; d < 12; ++d) {
      float4 w4 = ((const float4*)s_wi)[d * 128 + e4 * 16 + sub];
      p0[d] += xv0[e4].x * w4.x + xv0[e4].y * w4.y + xv0[e4].z * w4.z + xv0[e4].w * w4.w;
    }
  }
  // ---- reduce across the 16 lanes of the sample (same tree -> bitwise equal)
  #pragma unroll
  for (int d = 0; d < 12; ++d) {
    #pragma unroll
    for (int m = 1; m <= 8; m <<= 1) {
      p0[d] += __shfl_xor(p0[d], m, 16);
    }
    p0[d] += bin[d];
  }

  // ---- indices (bit 11-d set iff xp_d > 0)
  unsigned idx0 = 0u;
  #pragma unroll
  for (int d = 0; d < 12; ++d) {
    idx0 |= (p0[d] > 0.f ? 1u : 0u) << (11 - d);
  }
  if (sub == 0) {
    idx_out[i0] = (float)idx0;
    #pragma unroll
    for (int d = 0; d < 12; ++d) s_xp[wave][g][d] = p0[d];
  }

  // ---- out row: coalesced store partition (bitwise-proven)
  float sg0[12];
  #pragma unroll
  for (int d = 0; d < 12; ++d) sg0[d] = p0[d] > 0.f ? 1.f : -1.f;

  float4* or0 = (float4*)(out + (size_t)i0 * 512);
  #pragma unroll
  for (int e4 = 0; e4 < 8; ++e4) {
    float4 bo = ((const float4*)b_out)[e4 * 16 + sub];
    float4 o0 = bo;
    #pragma unroll
    for (int d = 0; d < 12; ++d) {
      float4 w4 = ((const float4*)s_wt)[d * 128 + e4 * 16 + sub];
      o0.x += sg0[d] * w4.x; o0.y += sg0[d] * w4.y; o0.z += sg0[d] * w4.z; o0.w += sg0[d] * w4.w;
    }
    or0[e4 * 16 + sub] = o0;
  }

  // ---- entropy: all 64 lanes process each of the wave's 4 samples
  float hacc = 0.f;
  #pragma unroll 1
  for (int s = 0; s < 4; ++s) {
    float xq[12];
    #pragma unroll
    for (int d = 0; d < 12; ++d) xq[d] = s_xp[wave][s][d];

    float hi = 0.f, lo = 0.f, ah = 0.f, al = 0.f;
    #pragma unroll
    for (int d = 0; d < 6; ++d) {
      int bh = (lane >> (5 - d)) & 1;
      hi += bh ? xq[d]     : -xq[d];
      lo += bh ? xq[6 + d] : -xq[6 + d];
      ah += fabsf(xq[d]);
      al += fabsf(xq[6 + d]);
    }
    float lhi = INVT2 * (hi - ah);   // <= 0, max over lanes == 0
    float llo = INVT2 * (lo - al);
    float ehi = __expf(lhi);
    float elo = __expf(llo);
    float Shi = ehi, Slo = elo;
    #pragma unroll
    for (int m = 1; m <= 32; m <<= 1) {
      Shi += __shfl_xor(Shi, m);
      Slo += __shfl_xor(Slo, m);
    }
    float phi = ehi / Shi;
    float psi = elo / Slo;
    float lnShi = __logf(Shi), lnSlo = __logf(Slo);
    hacc += phi * (lhi - lnShi) + psi * (llo - lnSlo);

    const int ws = wave * 4 + s;
    s_phi[ws][lane] = phi;
    s_psi[ws][lane] = psi;
  }

  // ---- per-sample-entropy: wave reduce, then block sum -> Hpart (no atomic)
  #pragma unroll
  for (int m = 1; m <= 32; m <<= 1) hacc += __shfl_xor(hacc, m);
  if (lane == 0) s_h[wave] = hacc;
  __syncthreads();   // also publishes s_phi/s_psi for phase B
  if (t == 0) {
    float hs = 0.f;
    for (int w2 = 0; w2 < 8; ++w2) hs += s_h[w2];
    Hpart[blockIdx.x] = hs;
  }

  // ---- phase B: avg_prob partial P[j][l] = sum_s phi[s][j]*psi[s][l]
  const int jb = (t >> 5) * 4;   // 16 j-tiles of 4
  const int lb = (t & 31) * 2;   // 32 l-tiles of 2
  float a00 = 0.f, a01 = 0.f, a10 = 0.f, a11 = 0.f;
  float a20 = 0.f, a21 = 0.f, a30 = 0.f, a31 = 0.f;
  #pragma unroll 4
  for (int s = 0; s < 32; ++s) {
    float4 ph = *(const float4*)&s_phi[s][jb];
    float2 ps = *(const float2*)&s_psi[s][lb];
    a00 += ph.x * ps.x; a01 += ph.x * ps.y;
    a10 += ph.y * ps.x; a11 += ph.y * ps.y;
    a20 += ph.z * ps.x; a21 += ph.z * ps.y;
    a30 += ph.w * ps.x; a31 += ph.w * ps.y;
  }
  float* Pr = P + (size_t)blockIdx.x * 4096;
  *(float2*)&Pr[(jb + 0) * 64 + lb] = make_float2(a00, a01);
  *(float2*)&Pr[(jb + 1) * 64 + lb] = make_float2(a10, a11);
  *(float2*)&Pr[(jb + 2) * 64 + lb] = make_float2(a20, a21);
  *(float2*)&Pr[(jb + 3) * 64 + lb] = make_float2(a30, a31);
}

// -------- K2: reduce P (coalesced) -> codebook entropy; sum Hpart; last block emits aux.
__global__ __launch_bounds__(256) void k_reduce(const float* __restrict__ P,
                                                const float* __restrict__ Hpart,
                                                float* __restrict__ scal,
                                                float* __restrict__ aux) {
  __shared__ float red[4][64];
  const int t = threadIdx.x;
  const int c = blockIdx.x * 64 + (t & 63);
  const int rg = t >> 6;                       // 4 row-groups of 128 rows
  float s = 0.f;
  #pragma unroll 8
  for (int j = 0; j < 128; ++j) s += P[(size_t)(rg * 128 + j) * 4096 + c];
  red[rg][t & 63] = s;
  __syncthreads();
  if (t < 64) {
    float tot = (red[0][t] + red[1][t]) + (red[2][t] + red[3][t]);
    float pb = tot * (1.f / (float)NS);
    float e = pb * __logf(fmaxf(pb, 1e-5f));   // p * log(clip(p, eps))
    #pragma unroll
    for (int m = 1; m <= 32; m <<= 1) e += __shfl_xor(e, m);
    if (t == 0) atomicAdd(&scal[1], e);
  }
  if (t == 128) {   // per-sample-entropy partial: 8 Hpart entries per block
    float ch = 0.f;
    #pragma unroll
    for (int k = 0; k < 8; ++k) ch += Hpart[blockIdx.x * 8 + k];
    atomicAdd(&scal[0], ch);
  }
  __syncthreads();
  __threadfence();
  if (t == 0) {
    unsigned done = atomicAdd((unsigned*)&scal[2], 1u);
    if (done == RBLK - 1) {   // last block: final combine
      float E = atomicAdd(&scal[1], 0.f);   // coherent reads via atomic
      float C = atomicAdd(&scal[0], 0.f);
      float per_sample_entropy = -C * (1.f / (float)NS);
      float codebook_entropy   = -E;
      aux[0] = 0.1f * (per_sample_entropy - codebook_entropy);
    }
  }
}

extern "C" void kernel_launch(void* const* d_in, const int* in_sizes, int n_in,
                              void* d_out, int out_size, void* d_ws, size_t ws_size,
                              hipStream_t stream) {
  const float* x     = (const float*)d_in[0];
  const float* w_in  = (const float*)d_in[1];
  const float* b_in  = (const float*)d_in[2];
  const float* w_out = (const float*)d_in[3];
  const float* b_out = (const float*)d_in[4];
  float* out = (float*)d_out;

  float* P     = (float*)d_ws;                  // 512*4096 f32 = 8 MB
  float* Hpart = P + (size_t)NBLK * 4096;       // 512 f32
  float* scal  = Hpart + NBLK;                  // {C_sum, E_sum, done}

  k_main<<<NBLK, 512, 0, stream>>>(x, w_in, b_in, w_out, b_out,
                                   out, out + NOUT, P, Hpart, scal);
  k_reduce<<<RBLK, 256, 0, stream>>>(P, Hpart, scal, out + AUXO);
}

// Round 10
// 114.037 us; speedup vs baseline: 1.5724x; 1.0242x over previous
//
#include <hip/hip_runtime.h>
#include <hip/hip_bf16.h>

// LFQ forward fused kernels for MI355X (gfx950).
// Outputs in d_out (float32): out[16384*512], indices[16384] (as float), aux_loss[1]
// ws layout: P[512][4096] partial avg_prob sums (8 MB), then 2 scalars {C_sum, E_sum}

#define NS    16384      // samples = 4*4096
#define NOUT  (NS*512)   // 8388608
#define AUXO  (NOUT+NS)  // 8404992
#define INVT2 200.0f     // 2 * inv_temperature
#define NBLK  512        // K1 blocks; 32 samples each (doubled grid for occupancy)

// -------- K1: xp, indices, out-projection, factorized softmax entropy + avg_prob partials
// One sample per lane-group (16 lanes); 4 samples/wave; 8 waves/block.
// LDS ~67 KB -> 2 blocks/CU at __launch_bounds__(512,4) -> 16 waves/CU.
__global__ __launch_bounds__(512, 4) void k_main(
    const float* __restrict__ x,
    const float* __restrict__ w_in,  const float* __restrict__ b_in,
    const float* __restrict__ w_out, const float* __restrict__ b_out,
    float* __restrict__ out, float* __restrict__ idx_out,
    float* __restrict__ P, float* __restrict__ Csum) {

  __shared__ float s_wi[6144];      // w_in swizzled: [d][e4][sub] float4s (dot partition)
  __shared__ float s_wt[6144];      // w_out^T swizzled for coalesced store partition
  __shared__ float s_phi[32][64];   // per-sample high-6-bit softmax probs
  __shared__ float s_psi[32][64];   // per-sample low-6-bit softmax probs
  __shared__ float s_xp[8][4][12];  // per-wave xp broadcast
  __shared__ float s_h[8];

  const int t = threadIdx.x;

  // stage weights.
  // s_wi (dot phase): element (d, e) with e = sub*32 + e4*4 + kk stored at
  //   f = ((d*128 + e4*16 + sub)*4 + kk)  -> lane-sub b128 reads conflict-free.
  // s_wt (out-proj): float f = d*512 + e holds w_out[e][d]; out-proj float4 read at
  //   index (d*128 + e4*16 + sub) yields e = (e4*16+sub)*4 + kk -> coalesced stores.
  for (int k = 0; k < 12; ++k) {
    int f  = t + k * 512;
    int kk = f & 3;
    int q  = f >> 2;
    int sub = q & 15, e4 = (q >> 4) & 7, d = q >> 7;
    int e  = sub * 32 + e4 * 4 + kk;
    s_wi[f] = w_in[d * 512 + e];
    s_wt[f] = w_out[t * 12 + k];   // f = t + k*512 -> e = t, d = k
  }
  __syncthreads();

  const int wave = t >> 6, lane = t & 63;
  const int g = lane >> 4, sub = lane & 15;

  float bin[12];
  #pragma unroll
  for (int d = 0; d < 12; ++d) bin[d] = b_in[d];

  // ---- one sample per lane
  const int i0 = blockIdx.x * 32 + wave * 4 + g;

  const float4* xr0 = (const float4*)(x + (size_t)i0 * 512 + sub * 32);
  float4 xv0[8];
  #pragma unroll
  for (int e4 = 0; e4 < 8; ++e4) xv0[e4] = xr0[e4];

  // ---- partial dots for 12 dims
  float p0[12];
  #pragma unroll
  for (int d = 0; d < 12; ++d) p0[d] = 0.f;
  #pragma unroll
  for (int e4 = 0; e4 < 8; ++e4) {
    #pragma unroll
    for (int d = 0; d < 12; ++d) {
      float4 w4 = ((const float4*)s_wi)[d * 128 + e4 * 16 + sub];
      p0[d] += xv0[e4].x * w4.x + xv0[e4].y * w4.y + xv0[e4].z * w4.z + xv0[e4].w * w4.w;
    }
  }
  // ---- reduce across the 16 lanes of the sample (same tree as before -> bitwise equal)
  #pragma unroll
  for (int d = 0; d < 12; ++d) {
    #pragma unroll
    for (int m = 1; m <= 8; m <<= 1) {
      p0[d] += __shfl_xor(p0[d], m, 16);
    }
    p0[d] += bin[d];
  }

  // ---- indices (bit 11-d set iff xp_d > 0)
  unsigned idx0 = 0u;
  #pragma unroll
  for (int d = 0; d < 12; ++d) {
    idx0 |= (p0[d] > 0.f ? 1u : 0u) << (11 - d);
  }
  if (sub == 0) {
    idx_out[i0] = (float)idx0;
    #pragma unroll
    for (int d = 0; d < 12; ++d) s_xp[wave][g][d] = p0[d];
  }

  // ---- out row: out[e] = b_out[e] + sum_d sign(xp_d) * w_out[e][d]
  // lane sub owns float4 index e4*16 + sub -> each store writes 256 contiguous bytes/group.
  float sg0[12];
  #pragma unroll
  for (int d = 0; d < 12; ++d) sg0[d] = p0[d] > 0.f ? 1.f : -1.f;

  float4* or0 = (float4*)(out + (size_t)i0 * 512);
  #pragma unroll
  for (int e4 = 0; e4 < 8; ++e4) {
    float4 bo = ((const float4*)b_out)[e4 * 16 + sub];
    float4 o0 = bo;
    #pragma unroll
    for (int d = 0; d < 12; ++d) {
      float4 w4 = ((const float4*)s_wt)[d * 128 + e4 * 16 + sub];
      o0.x += sg0[d] * w4.x; o0.y += sg0[d] * w4.y; o0.z += sg0[d] * w4.z; o0.w += sg0[d] * w4.w;
    }
    or0[e4 * 16 + sub] = o0;
  }

  // ---- entropy: all 64 lanes process each of the wave's 4 samples
  float hacc = 0.f;
  #pragma unroll 1
  for (int s = 0; s < 4; ++s) {
    float xq[12];
    #pragma unroll
    for (int d = 0; d < 12; ++d) xq[d] = s_xp[wave][s][d];

    float hi = 0.f, lo = 0.f, ah = 0.f, al = 0.f;
    #pragma unroll
    for (int d = 0; d < 6; ++d) {
      int bh = (lane >> (5 - d)) & 1;
      hi += bh ? xq[d]     : -xq[d];
      lo += bh ? xq[6 + d] : -xq[6 + d];
      ah += fabsf(xq[d]);
      al += fabsf(xq[6 + d]);
    }
    float lhi = INVT2 * (hi - ah);   // <= 0, max over lanes == 0
    float llo = INVT2 * (lo - al);
    float ehi = __expf(lhi);
    float elo = __expf(llo);
    float Shi = ehi, Slo = elo;
    #pragma unroll
    for (int m = 1; m <= 32; m <<= 1) {
      Shi += __shfl_xor(Shi, m);
      Slo += __shfl_xor(Slo, m);
    }
    float phi = ehi / Shi;
    float psi = elo / Slo;
    float lnShi = __logf(Shi), lnSlo = __logf(Slo);
    // factorized per-sample entropy: H = -(sum phi log phi + sum psi log psi)
    hacc += phi * (lhi - lnShi) + psi * (llo - lnSlo);

    const int ws = wave * 4 + s;
    s_phi[ws][lane] = phi;
    s_psi[ws][lane] = psi;
  }

  // ---- per-sample-entropy: wave reduce, then block reduce
  #pragma unroll
  for (int m = 1; m <= 32; m <<= 1) hacc += __shfl_xor(hacc, m);
  if (lane == 0) s_h[wave] = hacc;
  __syncthreads();   // also publishes s_phi/s_psi for phase B
  if (t == 0) {
    float hs = 0.f;
    for (int w2 = 0; w2 < 8; ++w2) hs += s_h[w2];
    atomicAdd(Csum, hs);
  }

  // ---- phase B: avg_prob partial P[j][l] = sum_s phi[s][j]*psi[s][l]
  // each thread owns a 4(j) x 2(l) code tile -> 8 accumulator registers
  const int jb = (t >> 5) * 4;   // 16 j-tiles of 4
  const int lb = (t & 31) * 2;   // 32 l-tiles of 2
  float a00 = 0.f, a01 = 0.f, a10 = 0.f, a11 = 0.f;
  float a20 = 0.f, a21 = 0.f, a30 = 0.f, a31 = 0.f;
  #pragma unroll 4
  for (int s = 0; s < 32; ++s) {
    float4 ph = *(const float4*)&s_phi[s][jb];
    float2 ps = *(const float2*)&s_psi[s][lb];
    a00 += ph.x * ps.x; a01 += ph.x * ps.y;
    a10 += ph.y * ps.x; a11 += ph.y * ps.y;
    a20 += ph.z * ps.x; a21 += ph.z * ps.y;
    a30 += ph.w * ps.x; a31 += ph.w * ps.y;
  }
  float* Pr = P + (size_t)blockIdx.x * 4096;
  *(float2*)&Pr[(jb + 0) * 64 + lb] = make_float2(a00, a01);
  *(float2*)&Pr[(jb + 1) * 64 + lb] = make_float2(a10, a11);
  *(float2*)&Pr[(jb + 2) * 64 + lb] = make_float2(a20, a21);
  *(float2*)&Pr[(jb + 3) * 64 + lb] = make_float2(a30, a31);
}

// -------- K2: reduce partials -> avg_prob, accumulate codebook entropy (exact, clipped)
__global__ __launch_bounds__(256) void k_reduce(const float* __restrict__ P,
                                                float* __restrict__ Esum) {
  __shared__ float red[16][17];
  __shared__ float ered[16];
  const int t = threadIdx.x;
  const int cl = t & 15, rg = t >> 4;
  const int c = blockIdx.x * 16 + cl;
  float s = 0.f;
  #pragma unroll
  for (int k = 0; k < 32; ++k) s += P[(size_t)(rg + k * 16) * 4096 + c];
  red[rg][cl] = s;
  __syncthreads();
  if (t < 16) {
    float tot = 0.f;
    #pragma unroll
    for (int r = 0; r < 16; ++r) tot += red[r][t];
    float pb = tot * (1.f / (float)NS);
    ered[t] = pb * __logf(fmaxf(pb, 1e-5f));   // p * log(clip(p, eps))
  }
  __syncthreads();
  if (t == 0) {
    float e = 0.f;
    #pragma unroll
    for (int r = 0; r < 16; ++r) e += ered[r];
    atomicAdd(Esum, e);
  }
}

// -------- K3: combine into aux_loss
__global__ void k_final(const float* __restrict__ Csum, const float* __restrict__ Esum,
                        float* __restrict__ aux) {
  if (threadIdx.x == 0) {
    float per_sample_entropy = -Csum[0] * (1.f / (float)NS);
    float codebook_entropy   = -Esum[0];
    aux[0] = 0.1f * (per_sample_entropy - codebook_entropy);
  }
}

extern "C" void kernel_launch(void* const* d_in, const int* in_sizes, int n_in,
                              void* d_out, int out_size, void* d_ws, size_t ws_size,
                              hipStream_t stream) {
  const float* x     = (const float*)d_in[0];
  const float* w_in  = (const float*)d_in[1];
  const float* b_in  = (const float*)d_in[2];
  const float* w_out = (const float*)d_in[3];
  const float* b_out = (const float*)d_in[4];
  float* out = (float*)d_out;

  float* P    = (float*)d_ws;                                    // 512*4096 f32 = 8 MB
  float* scal = (float*)((char*)d_ws + (size_t)NBLK * 4096 * 4); // {C_sum, E_sum}

  hipMemsetAsync(scal, 0, 2 * sizeof(float), stream);
  k_main<<<NBLK, 512, 0, stream>>>(x, w_in, b_in, w_out, b_out,
                                   out, out + NOUT, P, scal);
  k_reduce<<<256, 256, 0, stream>>>(P, scal + 1);
  k_final<<<1, 64, 0, stream>>>(scal, scal + 1, out + AUXO);
}